// Round 1
// baseline (239.728 us; speedup 1.0000x reference)
//
#include <hip/hip_runtime.h>
#include <cstdint>

// ---------------- problem constants ----------------
#define BATCH 8
#define NCLS  80
#define KTOP  1000
#define KPAD  1024
#define NW    16            // 64-bit words covering KPAD
#define NPOS  21824         // 128^2 + 64^2 + 32^2 + 16^2 + 8^2

// ---------------- workspace layout (bytes) ----------------
#define OFF_KEYS     0
#define OFF_BOXES    (BATCH*NPOS*8)                    // 1,396,736
#define OFF_KIND     (OFF_BOXES + BATCH*NPOS*16)       // 4,190,208
#define OFF_SELBOX   (OFF_KIND + BATCH*NPOS*4)         // 4,888,576
#define OFF_SELKIND  (OFF_SELBOX + BATCH*KPAD*16)      // 5,019,648
#define OFF_SELSCORE (OFF_SELKIND + BATCH*KPAD*4)      // 5,052,416
#define OFF_MASK     (OFF_SELSCORE + BATCH*KPAD*4)     // 5,085,184
// total = OFF_MASK + BATCH*KPAD*NW*8 = 6,133,760 bytes

// ============================================================
// Kernel 1: decode — per (batch, position): score=max over 80
// classes, kind=first argmax, box decode; emit 64-bit sort key.
// ============================================================
__global__ __launch_bounds__(256) void k_decode(
    const float* __restrict__ cls0, const float* __restrict__ cls1,
    const float* __restrict__ cls2, const float* __restrict__ cls3,
    const float* __restrict__ cls4,
    const float* __restrict__ reg0, const float* __restrict__ reg1,
    const float* __restrict__ reg2, const float* __restrict__ reg3,
    const float* __restrict__ reg4,
    char* __restrict__ ws)
{
#pragma clang fp contract(off)
    int b = blockIdx.y;
    int p = blockIdx.x * 256 + threadIdx.x;
    if (p >= NPOS) return;

    int off, wlog; float stridef;
    const float* cls; const float* reg;
    if (p < 16384)      { off = 0;     wlog = 7; stridef = 8.f;   cls = cls0; reg = reg0; }
    else if (p < 20480) { off = 16384; wlog = 6; stridef = 16.f;  cls = cls1; reg = reg1; }
    else if (p < 21504) { off = 20480; wlog = 5; stridef = 32.f;  cls = cls2; reg = reg2; }
    else if (p < 21760) { off = 21504; wlog = 4; stridef = 64.f;  cls = cls3; reg = reg3; }
    else                { off = 21760; wlog = 3; stridef = 128.f; cls = cls4; reg = reg4; }

    int q  = p - off;
    int hw = 1 << (2 * wlog);
    int x  = q & ((1 << wlog) - 1);
    int y  = q >> wlog;

    // score = max over classes, kind = first argmax (strict >)
    const float* cp = cls + (size_t)(b * NCLS) * hw + q;
    float m = -1.f; int arg = 0;
    #pragma unroll 4
    for (int c = 0; c < NCLS; ++c) {
        float v = cp[(size_t)c * hw];
        if (v > m) { m = v; arg = c; }
    }
    float score = (m > 0.05f) ? m : 0.0f;
    // key: descending score, ties -> lower position index first
    uint64_t key = ((uint64_t)__float_as_uint(score) << 32)
                 | (uint32_t)(0xFFFFFFFFu - (uint32_t)p);

    // box decode (exact: stride is power of 2, no contraction)
    const float* rp = reg + (size_t)(b * 4) * hw + q;
    float l  = rp[0]          * stridef;
    float t  = rp[(size_t)hw]   * stridef;
    float r  = rp[(size_t)2*hw] * stridef;
    float bo = rp[(size_t)3*hw] * stridef;
    float cx = ((float)x + 0.5f) * stridef;
    float cy = ((float)y + 0.5f) * stridef;
    float4 box = make_float4(cx - l, cy - t, cx + r, cy + bo);

    uint64_t* keys = (uint64_t*)(ws + OFF_KEYS);
    float4*  boxes = (float4*)(ws + OFF_BOXES);
    float*   kind  = (float*)(ws + OFF_KIND);
    size_t gi = (size_t)b * NPOS + p;
    keys[gi]  = key;
    boxes[gi] = box;
    kind[gi]  = (float)arg;
}

// ============================================================
// Kernel 2: per-batch exact top-1000 — 8-bit MSD radix select of
// the 1000th-largest 64-bit key (keys are all distinct), gather,
// bitonic sort 1024 descending in LDS, write selected arrays.
// ============================================================
__global__ __launch_bounds__(1024) void k_select(char* __restrict__ ws)
{
    int b   = blockIdx.x;
    int tid = threadIdx.x;
    const uint64_t* keys = (const uint64_t*)(ws + OFF_KEYS) + (size_t)b * NPOS;

    __shared__ unsigned int hist[256];
    __shared__ uint64_t sPrefix;
    __shared__ int sRank;
    __shared__ unsigned int sCnt;
    __shared__ uint64_t sKey[KPAD];

    if (tid == 0) { sPrefix = 0; sRank = KTOP; }

    for (int pass = 0; pass < 8; ++pass) {
        if (tid < 256) hist[tid] = 0;
        __syncthreads();
        uint64_t prefix = sPrefix;
        int shift = 56 - 8 * pass;
        for (int i = tid; i < NPOS; i += 1024) {
            uint64_t k = keys[i];
            bool match = (pass == 0) || ((k >> (shift + 8)) == prefix);
            if (match) atomicAdd(&hist[(unsigned)(k >> shift) & 255u], 1u);
        }
        __syncthreads();
        if (tid == 0) {
            int r = sRank;
            int d = 255;
            for (; d > 0; --d) {
                int c = (int)hist[d];
                if (r <= c) break;
                r -= c;
            }
            sRank = r;
            sPrefix = (prefix << 8) | (unsigned)d;
        }
        __syncthreads();
    }
    uint64_t T = sPrefix;   // exact 1000th-largest key

    sKey[tid] = 0;
    if (tid == 0) sCnt = 0;
    __syncthreads();
    for (int i = tid; i < NPOS; i += 1024) {
        uint64_t k = keys[i];
        if (k >= T) {
            unsigned slot = atomicAdd(&sCnt, 1u);
            if (slot < KPAD) sKey[slot] = k;
        }
    }
    __syncthreads();

    // bitonic sort, descending
    for (int kk = 2; kk <= KPAD; kk <<= 1) {
        for (int j = kk >> 1; j > 0; j >>= 1) {
            int ixj = tid ^ j;
            if (ixj > tid) {
                uint64_t a = sKey[tid], c = sKey[ixj];
                bool up = ((tid & kk) == 0);
                bool sw = up ? (a < c) : (a > c);
                if (sw) { sKey[tid] = c; sKey[ixj] = a; }
            }
            __syncthreads();
        }
    }

    const float4* boxes = (const float4*)(ws + OFF_BOXES) + (size_t)b * NPOS;
    const float*  kind  = (const float*)(ws + OFF_KIND)  + (size_t)b * NPOS;
    float4* selbox  = (float4*)(ws + OFF_SELBOX)  + (size_t)b * KPAD;
    float* selkind  = (float*)(ws + OFF_SELKIND)  + (size_t)b * KPAD;
    float* selscore = (float*)(ws + OFF_SELSCORE) + (size_t)b * KPAD;

    uint64_t k = sKey[tid];
    if (tid < KTOP) {
        uint32_t idx = 0xFFFFFFFFu - (uint32_t)(k & 0xFFFFFFFFull);
        selbox[tid]   = boxes[idx];
        selkind[tid]  = kind[idx];
        selscore[tid] = __uint_as_float((uint32_t)(k >> 32));
    } else {
        selbox[tid]   = make_float4(0.f, 0.f, 0.f, 0.f);
        selkind[tid]  = 0.f;
        selscore[tid] = 0.f;
    }
}

// ============================================================
// Kernel 3: suppression bitmatrix, column-major:
// colmask[b][j][wi] bit t  <=>  i=wi*64+t suppresses j
// (i<j, same class, IoU>0.5 with reference-exact arithmetic).
// ============================================================
__global__ __launch_bounds__(256) void k_mask(char* __restrict__ ws)
{
#pragma clang fp contract(off)
    int b = blockIdx.y;
    __shared__ float4 sbox[KPAD];
    __shared__ float  sarea[KPAD];
    __shared__ float  skind[KPAD];

    const float4* selbox = (const float4*)(ws + OFF_SELBOX) + (size_t)b * KPAD;
    const float*  selkind = (const float*)(ws + OFF_SELKIND) + (size_t)b * KPAD;
    for (int i = threadIdx.x; i < KPAD; i += 256) {
        float4 bx = selbox[i];
        sbox[i]  = bx;
        sarea[i] = fmaxf(bx.z - bx.x, 0.f) * fmaxf(bx.w - bx.y, 0.f);
        skind[i] = selkind[i];
    }
    __syncthreads();

    int wid = blockIdx.x * 256 + threadIdx.x;   // 0..16383
    int j  = wid >> 4;
    int wi = wid & 15;
    uint64_t word = 0;
    if (wi * 64 < j) {
        float4 bj = sbox[j];
        float areaj = sarea[j];
        float kj = skind[j];
        int tmax = min(64, j - wi * 64);
        for (int t = 0; t < tmax; ++t) {
            int i = wi * 64 + t;
            if (skind[i] == kj) {
                float4 bi = sbox[i];
                float xx1 = fmaxf(bi.x, bj.x);
                float yy1 = fmaxf(bi.y, bj.y);
                float xx2 = fminf(bi.z, bj.z);
                float yy2 = fminf(bi.w, bj.w);
                float iw = fmaxf(xx2 - xx1, 0.f);
                float ih = fmaxf(yy2 - yy1, 0.f);
                float inter = iw * ih;
                float den = sarea[i] + areaj;   // area[i] + area
                den = den - inter;              // - inter
                den = den + 1e-9f;              // + 1e-9
                float iou = inter / den;        // IEEE divide
                if (iou > 0.5f) word |= (1ull << t);
            }
        }
    }
    uint64_t* colmask = (uint64_t*)(ws + OFF_MASK) + (size_t)b * KPAD * NW;
    colmask[(size_t)j * NW + wi] = word;
}

// ============================================================
// Kernel 4: greedy-NMS fixpoint via Jacobi iteration on the
// bitmatrix (prefix-stabilizes; == sequential greedy result),
// then write (B, 1000, 6) output.
// ============================================================
__global__ __launch_bounds__(1024) void k_scan_out(char* __restrict__ ws,
                                                   float* __restrict__ out)
{
    int b    = blockIdx.x;
    int tid  = threadIdx.x;
    int lane = tid & 63;
    int wave = tid >> 6;

    const uint64_t* colmask = (const uint64_t*)(ws + OFF_MASK) + (size_t)b * KPAD * NW;
    uint64_t c[NW];
    #pragma unroll
    for (int wi = 0; wi < NW; ++wi) c[wi] = colmask[(size_t)tid * NW + wi];

    __shared__ uint64_t kw[NW];
    __shared__ int changed;

    bool nk = (tid < KTOP);
    unsigned long long ball = __ballot(nk);
    if (lane == 0) kw[wave] = ball;
    __syncthreads();

    for (int round = 0; round < 1100; ++round) {
        uint64_t s = 0;
        #pragma unroll
        for (int wi = 0; wi < NW; ++wi) s |= (kw[wi] & c[wi]);
        nk = (tid < KTOP) && (s == 0);
        unsigned long long nb = __ballot(nk);
        __syncthreads();                 // everyone done reading kw
        if (tid == 0) changed = 0;
        __syncthreads();
        if (lane == 0) {
            if (nb != kw[wave]) changed = 1;
            kw[wave] = nb;
        }
        __syncthreads();
        if (!changed) break;
    }

    if (tid < KTOP) {
        const float4* selbox  = (const float4*)(ws + OFF_SELBOX)  + (size_t)b * KPAD;
        const float*  selkind = (const float*)(ws + OFF_SELKIND)  + (size_t)b * KPAD;
        const float*  selscore= (const float*)(ws + OFF_SELSCORE) + (size_t)b * KPAD;
        float4 bx = selbox[tid];
        float  sc = selscore[tid];
        bool kept = nk && (sc > 0.f);
        float* o = out + ((size_t)b * KTOP + tid) * 6;
        o[0] = bx.x; o[1] = bx.y; o[2] = bx.z; o[3] = bx.w;
        o[4] = selkind[tid];
        o[5] = kept ? sc : 0.f;
    }
}

// ============================================================
extern "C" void kernel_launch(void* const* d_in, const int* in_sizes, int n_in,
                              void* d_out, int out_size, void* d_ws, size_t ws_size,
                              hipStream_t stream)
{
    // setup_inputs order: cls0,cnt0,reg0, cls1,cnt1,reg1, ... (cnt unused)
    const float* cls[5] = { (const float*)d_in[0], (const float*)d_in[3],
                            (const float*)d_in[6], (const float*)d_in[9],
                            (const float*)d_in[12] };
    const float* reg[5] = { (const float*)d_in[2], (const float*)d_in[5],
                            (const float*)d_in[8], (const float*)d_in[11],
                            (const float*)d_in[14] };
    char*  ws  = (char*)d_ws;
    float* out = (float*)d_out;

    dim3 g1((NPOS + 255) / 256, BATCH);
    k_decode<<<g1, 256, 0, stream>>>(cls[0], cls[1], cls[2], cls[3], cls[4],
                                     reg[0], reg[1], reg[2], reg[3], reg[4], ws);
    k_select<<<BATCH, 1024, 0, stream>>>(ws);
    dim3 g3(64, BATCH);
    k_mask<<<g3, 256, 0, stream>>>(ws);
    k_scan_out<<<BATCH, 1024, 0, stream>>>(ws, out);
}